// Round 1
// baseline (364.308 us; speedup 1.0000x reference)
//
#include <hip/hip_runtime.h>
#include <hip/hip_bf16.h>
#include <stdint.h>

// Problem constants
#define M_DIM 8192   // B*S = 4*2048
#define N_C   4096   // contraction dim (N in reference)
#define K_OUT 4096   // output features (K in reference)
#define NGRP  32

typedef __attribute__((ext_vector_type(8))) short bf16x8;
typedef __attribute__((ext_vector_type(4))) float f32x4;

// fp32 -> bf16, round-to-nearest-even (inputs are finite)
__device__ __forceinline__ unsigned short f2b(float f) {
  unsigned u = __float_as_uint(f);
  return (unsigned short)((u + 0x7fffu + ((u >> 16) & 1u)) >> 16);
}

__device__ __forceinline__ void gload_lds16(const void* g, void* l) {
  __builtin_amdgcn_global_load_lds(
      (const __attribute__((address_space(1))) void*)g,
      (__attribute__((address_space(3))) void*)l,
      16, 0, 0);
}

// ---- x fp32 -> bf16 (33.5M elements, 8/thread/iter) ----
__global__ void convert_x_kernel(const float* __restrict__ x,
                                 unsigned short* __restrict__ xb) {
  const int total = (M_DIM * N_C) / 8;
  const int stride = gridDim.x * blockDim.x;
  for (int i = blockIdx.x * blockDim.x + threadIdx.x; i < total; i += stride) {
    const float4* p = (const float4*)(x + (size_t)i * 8);
    float4 a = p[0];
    float4 b = p[1];
    union { unsigned short u[8]; uint4 v; } o;
    o.u[0] = f2b(a.x); o.u[1] = f2b(a.y); o.u[2] = f2b(a.z); o.u[3] = f2b(a.w);
    o.u[4] = f2b(b.x); o.u[5] = f2b(b.y); o.u[6] = f2b(b.z); o.u[7] = f2b(b.w);
    *(uint4*)(xb + (size_t)i * 8) = o.v;
  }
}

// ---- W dequant: (q - zero)*scale*mu2[k]*mu1[n] -> bf16 [K_OUT][N_C] ----
__global__ void dequant_w_kernel(const int* __restrict__ Wq,
                                 const float* __restrict__ scales,
                                 const float* __restrict__ zeros,
                                 const float* __restrict__ mu1,
                                 const float* __restrict__ mu2,
                                 unsigned short* __restrict__ wb) {
  const int total = (K_OUT * N_C) / 8;
  const int stride = gridDim.x * blockDim.x;
  for (int i = blockIdx.x * blockDim.x + threadIdx.x; i < total; i += stride) {
    const int k  = i >> 9;          // 512 chunks of 8 per row
    const int nc = (i & 511) << 3;  // column base
    const int g  = nc >> 7;         // group index (group size 128)
    const float s = scales[k * NGRP + g];
    const float z = zeros[k * NGRP + g];
    const float f  = s * mu2[k];
    const float zf = z * f;         // w = (q*f - zf) * mu1[n]
    const int4* q4 = (const int4*)(Wq + (size_t)k * N_C + nc);
    int4 q0 = q4[0], q1 = q4[1];
    const float4* m4 = (const float4*)(mu1 + nc);
    float4 m0 = m4[0], m1 = m4[1];
    union { unsigned short u[8]; uint4 v; } o;
    o.u[0] = f2b(((float)q0.x * f - zf) * m0.x);
    o.u[1] = f2b(((float)q0.y * f - zf) * m0.y);
    o.u[2] = f2b(((float)q0.z * f - zf) * m0.z);
    o.u[3] = f2b(((float)q0.w * f - zf) * m0.w);
    o.u[4] = f2b(((float)q1.x * f - zf) * m1.x);
    o.u[5] = f2b(((float)q1.y * f - zf) * m1.y);
    o.u[6] = f2b(((float)q1.z * f - zf) * m1.z);
    o.u[7] = f2b(((float)q1.w * f - zf) * m1.w);
    *(uint4*)(wb + (size_t)i * 8) = o.v;
  }
}

// ---- bf16 GEMM: out[m][k] = sum_n Xb[m][n]*Wb[k][n] + bias[k] ----
// m97 structure: 128x128 tile, BK=64, 4 waves (2x2), 4x4 acc of 16x16x32 MFMA,
// global_load_lds width-16 staging, single-buffered LDS, 2 barriers/K-step.
__global__ __launch_bounds__(256, 2) void gemm_bf16_kernel(
    const unsigned short* __restrict__ Xb,   // [M_DIM][N_C] bf16
    const unsigned short* __restrict__ Wb,   // [K_OUT][N_C] bf16
    const float* __restrict__ bias,          // [K_OUT]
    float* __restrict__ out) {               // [M_DIM][K_OUT]
  __shared__ unsigned short sA[128 * 64];    // 16 KB
  __shared__ unsigned short sB[128 * 64];    // 16 KB

  const int k0 = blockIdx.x * 128;   // output-feature tile
  const int m0 = blockIdx.y * 128;   // row tile
  const int t = threadIdx.x;
  const int wv = t >> 6;
  const int lane = t & 63;
  const int wr = wv >> 1;            // wave row (0..1) -> 64 rows
  const int wc = wv & 1;             // wave col (0..1) -> 64 cols

  f32x4 acc[4][4] = {};

  // Staging geometry: per round r (0..3), wave wv stages 1024 contiguous bytes
  // at LDS offset r*4096 + wv*1024; lane i supplies 16 B at +i*16.
  const int soff = wv * 1024 + lane * 16;      // byte offset within round-0 slab

  for (int nk = 0; nk < N_C; nk += 64) {
    __syncthreads();   // previous tile's reads done before overwrite
#pragma unroll
    for (int r = 0; r < 4; ++r) {
      const int off  = r * 4096 + soff;        // byte offset within 16 KB tile
      const int row  = off >> 7;               // 128 B per row (64 bf16)
      const int colb = off & 127;
      gload_lds16((const char*)Xb + (size_t)(m0 + row) * (N_C * 2) + (size_t)nk * 2 + colb,
                  (char*)sA + r * 4096 + wv * 1024);
      gload_lds16((const char*)Wb + (size_t)(k0 + row) * (N_C * 2) + (size_t)nk * 2 + colb,
                  (char*)sB + r * 4096 + wv * 1024);
    }
    __syncthreads();   // vmcnt(0) drained by compiler before barrier

#pragma unroll
    for (int kk = 0; kk < 2; ++kk) {
      const int col = kk * 32 + (lane >> 4) * 8;   // element col within 64
      bf16x8 af[4], bfr[4];
#pragma unroll
      for (int i = 0; i < 4; ++i) {
        const int ra = wr * 64 + i * 16 + (lane & 15);
        af[i] = *(const bf16x8*)(sA + ra * 64 + col);
        const int rb = wc * 64 + i * 16 + (lane & 15);
        bfr[i] = *(const bf16x8*)(sB + rb * 64 + col);
      }
#pragma unroll
      for (int i = 0; i < 4; ++i)
#pragma unroll
        for (int j = 0; j < 4; ++j)
          acc[i][j] = __builtin_amdgcn_mfma_f32_16x16x32_bf16(af[i], bfr[j], acc[i][j], 0, 0, 0);
    }
  }

  // Epilogue: C/D layout col=lane&15, row=(lane>>4)*4+reg (m89/m91 verified)
#pragma unroll
  for (int i = 0; i < 4; ++i) {
    const int mrow = m0 + wr * 64 + i * 16 + (lane >> 4) * 4;
#pragma unroll
    for (int j = 0; j < 4; ++j) {
      const int kc = k0 + wc * 64 + j * 16 + (lane & 15);
      const float b = bias[kc];
#pragma unroll
      for (int r = 0; r < 4; ++r) {
        out[(size_t)(mrow + r) * K_OUT + kc] = acc[i][j][r] + b;
      }
    }
  }
}

extern "C" void kernel_launch(void* const* d_in, const int* in_sizes, int n_in,
                              void* d_out, int out_size, void* d_ws, size_t ws_size,
                              hipStream_t stream) {
  const float* x      = (const float*)d_in[0];
  const int*   Wq     = (const int*)d_in[1];
  const float* scales = (const float*)d_in[2];
  const float* zeros  = (const float*)d_in[3];
  const float* mu1    = (const float*)d_in[4];
  const float* mu2    = (const float*)d_in[5];
  const float* bias   = (const float*)d_in[6];
  float* out = (float*)d_out;

  // Workspace: xb bf16 [M_DIM][N_C] (64 MiB) then wb bf16 [K_OUT][N_C] (32 MiB)
  unsigned short* xb = (unsigned short*)d_ws;
  unsigned short* wb = xb + (size_t)M_DIM * N_C;

  convert_x_kernel<<<2048, 256, 0, stream>>>(x, xb);
  dequant_w_kernel<<<2048, 256, 0, stream>>>(Wq, scales, zeros, mu1, mu2, wb);

  dim3 grid(K_OUT / 128, M_DIM / 128);   // 32 x 64 = 2048 blocks
  gemm_bf16_kernel<<<grid, 256, 0, stream>>>(xb, wb, bias, out);
}

// Round 2
// 298.126 us; speedup vs baseline: 1.2220x; 1.2220x over previous
//
#include <hip/hip_runtime.h>
#include <hip/hip_bf16.h>
#include <stdint.h>

// Problem constants
#define M_DIM 8192   // B*S = 4*2048
#define N_C   4096   // contraction dim (N in reference)
#define K_OUT 4096   // output features (K in reference)
#define NGRP  32
#define NT    (N_C / 32)   // 128 K-tiles of 32

typedef __attribute__((ext_vector_type(8))) short bf16x8;
typedef __attribute__((ext_vector_type(4))) float f32x4;

// fp32 -> bf16, round-to-nearest-even (inputs are finite)
__device__ __forceinline__ unsigned short f2b(float f) {
  unsigned u = __float_as_uint(f);
  return (unsigned short)((u + 0x7fffu + ((u >> 16) & 1u)) >> 16);
}

__device__ __forceinline__ void gload_lds16(const void* g, void* l) {
  __builtin_amdgcn_global_load_lds(
      (const __attribute__((address_space(1))) void*)g,
      (__attribute__((address_space(3))) void*)l,
      16, 0, 0);
}

// ---- x fp32 -> bf16 ----
__global__ void convert_x_kernel(const float* __restrict__ x,
                                 unsigned short* __restrict__ xb) {
  const int total = (M_DIM * N_C) / 8;
  const int stride = gridDim.x * blockDim.x;
  for (int i = blockIdx.x * blockDim.x + threadIdx.x; i < total; i += stride) {
    const float4* p = (const float4*)(x + (size_t)i * 8);
    float4 a = p[0];
    float4 b = p[1];
    union { unsigned short u[8]; uint4 v; } o;
    o.u[0] = f2b(a.x); o.u[1] = f2b(a.y); o.u[2] = f2b(a.z); o.u[3] = f2b(a.w);
    o.u[4] = f2b(b.x); o.u[5] = f2b(b.y); o.u[6] = f2b(b.z); o.u[7] = f2b(b.w);
    *(uint4*)(xb + (size_t)i * 8) = o.v;
  }
}

// ---- W dequant -> bf16 [K_OUT][N_C] ----
__global__ void dequant_w_kernel(const int* __restrict__ Wq,
                                 const float* __restrict__ scales,
                                 const float* __restrict__ zeros,
                                 const float* __restrict__ mu1,
                                 const float* __restrict__ mu2,
                                 unsigned short* __restrict__ wb) {
  const int total = (K_OUT * N_C) / 8;
  const int stride = gridDim.x * blockDim.x;
  for (int i = blockIdx.x * blockDim.x + threadIdx.x; i < total; i += stride) {
    const int k  = i >> 9;
    const int nc = (i & 511) << 3;
    const int g  = nc >> 7;
    const float s = scales[k * NGRP + g];
    const float z = zeros[k * NGRP + g];
    const float f  = s * mu2[k];
    const float zf = z * f;
    const int4* q4 = (const int4*)(Wq + (size_t)k * N_C + nc);
    int4 q0 = q4[0], q1 = q4[1];
    const float4* m4 = (const float4*)(mu1 + nc);
    float4 m0 = m4[0], m1 = m4[1];
    union { unsigned short u[8]; uint4 v; } o;
    o.u[0] = f2b(((float)q0.x * f - zf) * m0.x);
    o.u[1] = f2b(((float)q0.y * f - zf) * m0.y);
    o.u[2] = f2b(((float)q0.z * f - zf) * m0.z);
    o.u[3] = f2b(((float)q0.w * f - zf) * m0.w);
    o.u[4] = f2b(((float)q1.x * f - zf) * m1.x);
    o.u[5] = f2b(((float)q1.y * f - zf) * m1.y);
    o.u[6] = f2b(((float)q1.z * f - zf) * m1.z);
    o.u[7] = f2b(((float)q1.w * f - zf) * m1.w);
    *(uint4*)(wb + (size_t)i * 8) = o.v;
  }
}

// ---- Deep-pipelined bf16 GEMM: out[m][n] = sum_k Xb[m][k]*Wb[n][k] + bias[n]
// 256x256 tile, BK=32, 8 waves (2Mx4N, per-wave 128x64), 4 LDS buffers
// (4 x (16KB A + 16KB B) = 128 KB), prefetch depth 3, counted vmcnt(8),
// one raw s_barrier per K-tile, XOR-swizzled LDS (slot ^= (row>>1)&3) with
// pre-swizzled global source (rule #21: linear gload_lds dest + inv-swz src
// + swz ds_read).
__global__ __launch_bounds__(512) void gemm_bf16_kernel(
    const unsigned short* __restrict__ Xb,   // [M_DIM][N_C] bf16
    const unsigned short* __restrict__ Wb,   // [K_OUT][N_C] bf16
    const float* __restrict__ bias,          // [K_OUT]
    float* __restrict__ out) {               // [M_DIM][K_OUT]
  __shared__ unsigned short smem[65536];     // 128 KiB: 4 bufs x 32 KiB

  // XCD-aware bijective swizzle: 512 blocks, 8 XCDs, 64 per XCD
  const int bid = blockIdx.x;
  const int swz = (bid & 7) * 64 + (bid >> 3);
  const int n0 = (swz & 15) * 256;   // output-feature tile (16 tiles)
  const int m0 = (swz >> 4) * 256;   // row tile (32 tiles)

  const int tid = threadIdx.x;
  const int w   = tid >> 6;
  const int l   = tid & 63;
  const int wr  = w >> 2;     // 0..1 -> 128 rows each
  const int wc  = w & 3;      // 0..3 -> 64 cols each

  // ---- staging sources (pre-swizzled per-lane global addresses) ----
  // LDS phys byte P = (e*8+w)*1024 + l*16 within a 16KB region; the data
  // belonging there is logical row r = P>>6, slot sl = ((P>>4)&3) ^ ((r>>1)&3).
  const char* Xc = (const char*)Xb;
  const char* Wc = (const char*)Wb;
  const char* srcA[2];
  const char* srcB[2];
  int dstOff[2];
#pragma unroll
  for (int e = 0; e < 2; ++e) {
    const int P  = (e * 8 + w) * 1024 + l * 16;
    const int r  = P >> 6;
    const int sl = ((P >> 4) & 3) ^ ((r >> 1) & 3);
    srcA[e] = Xc + (size_t)(m0 + r) * (N_C * 2) + sl * 16;
    srcB[e] = Wc + (size_t)(n0 + r) * (N_C * 2) + sl * 16;
    dstOff[e] = (e * 8 + w) * 1024;   // wave-uniform LDS byte offset
  }

  // ---- swizzled ds_read offsets (ushort units, within one 32KB buffer) ----
  int offa[8], offb[4];
#pragma unroll
  for (int i = 0; i < 8; ++i) {
    const int r  = wr * 128 + i * 16 + (l & 15);
    const int sl = (l >> 4) ^ ((r >> 1) & 3);
    offa[i] = (r * 64 + sl * 16) >> 1;
  }
#pragma unroll
  for (int j = 0; j < 4; ++j) {
    const int r  = wc * 64 + j * 16 + (l & 15);
    const int sl = (l >> 4) ^ ((r >> 1) & 3);
    offb[j] = (16384 + r * 64 + sl * 16) >> 1;
  }

  f32x4 acc[8][4] = {};
  char* ldsc = (char*)smem;

#define STAGE(tt)                                                            \
  { const int sb = ((tt) & 3) * 32768; const size_t ko = (size_t)(tt) * 64;  \
    gload_lds16(srcA[0] + ko, ldsc + sb + dstOff[0]);                        \
    gload_lds16(srcA[1] + ko, ldsc + sb + dstOff[1]);                        \
    gload_lds16(srcB[0] + ko, ldsc + sb + 16384 + dstOff[0]);                \
    gload_lds16(srcB[1] + ko, ldsc + sb + 16384 + dstOff[1]); }

  // Prologue: stage tiles 0,1,2 (12 loads in flight)
  STAGE(0)
  STAGE(1)
  STAGE(2)

  // Per-iteration contract: at top of iteration t, my outstanding vmem =
  // stages of t+1,t+2 (8 loads) -> vmcnt(8) proves tile t landed (for me);
  // the barrier then proves it for all waves. stage(t+3) overwrites
  // buf[(t-1)&3], whose reads were lgkm-drained by every wave before it
  // passed this iteration's barrier.
#define KSTEP(VMSTR, tt, DOSTAGE)                                            \
  { asm volatile("s_waitcnt vmcnt(" VMSTR ")\n\ts_barrier" ::: "memory");    \
    const int bufo = ((tt) & 3) * 16384;                                     \
    bf16x8 af[8]; bf16x8 bfv[4];                                             \
    _Pragma("unroll") for (int i = 0; i < 8; ++i)                            \
      af[i] = *(const bf16x8*)(smem + bufo + offa[i]);                       \
    _Pragma("unroll") for (int j = 0; j < 4; ++j)                            \
      bfv[j] = *(const bf16x8*)(smem + bufo + offb[j]);                      \
    if (DOSTAGE) STAGE((tt) + 3)                                             \
    __builtin_amdgcn_s_setprio(1);                                           \
    _Pragma("unroll") for (int i = 0; i < 8; ++i)                            \
      _Pragma("unroll") for (int j = 0; j < 4; ++j)                          \
        acc[i][j] = __builtin_amdgcn_mfma_f32_16x16x32_bf16(af[i], bfv[j],   \
                                                            acc[i][j], 0, 0, 0); \
    __builtin_amdgcn_s_setprio(0); }

#pragma unroll 1
  for (int kt = 0; kt < NT - 3; ++kt) KSTEP("8", kt, 1)
  KSTEP("8", NT - 3, 0)
  KSTEP("4", NT - 2, 0)
  KSTEP("0", NT - 1, 0)

#undef KSTEP
#undef STAGE

  // Epilogue: C/D layout col=lane&15, row=(lane>>4)*4+reg (verified R1)
#pragma unroll
  for (int j = 0; j < 4; ++j) {
    const int col = n0 + wc * 64 + j * 16 + (l & 15);
    const float bv = bias[col];
#pragma unroll
    for (int i = 0; i < 8; ++i) {
      const int row = m0 + wr * 128 + i * 16 + (l >> 4) * 4;
#pragma unroll
      for (int rr = 0; rr < 4; ++rr)
        out[(size_t)(row + rr) * K_OUT + col] = acc[i][j][rr] + bv;
    }
  }
}

extern "C" void kernel_launch(void* const* d_in, const int* in_sizes, int n_in,
                              void* d_out, int out_size, void* d_ws, size_t ws_size,
                              hipStream_t stream) {
  const float* x      = (const float*)d_in[0];
  const int*   Wq     = (const int*)d_in[1];
  const float* scales = (const float*)d_in[2];
  const float* zeros  = (const float*)d_in[3];
  const float* mu1    = (const float*)d_in[4];
  const float* mu2    = (const float*)d_in[5];
  const float* bias   = (const float*)d_in[6];
  float* out = (float*)d_out;

  unsigned short* xb = (unsigned short*)d_ws;
  unsigned short* wb = xb + (size_t)M_DIM * N_C;

  convert_x_kernel<<<2048, 256, 0, stream>>>(x, xb);
  dequant_w_kernel<<<2048, 256, 0, stream>>>(Wq, scales, zeros, mu1, mu2, wb);

  dim3 grid((M_DIM / 256) * (K_OUT / 256));   // 512 blocks
  gemm_bf16_kernel<<<grid, 512, 0, stream>>>(xb, wb, bias, out);
}